// Round 1
// baseline (542.566 us; speedup 1.0000x reference)
//
#include <hip/hip_runtime.h>

// Problem shape (fixed by setup_inputs): x [B=512, L=512, C=256] f32,
// pred_len = 96 -> out [B, 608, C] f32.
// slope = (sum_ty - (sum_t/n)*sum_y) / denom ; intercept = (sum_y - slope*sum_t)/n
// with n=512: sum_t = 130816 (exact f32), sum_t/n = 255.5,
// sum_t2 = 44608256, denom = sum_t2 - sum_t^2/n = 11184768 (exact f32).

constexpr int Bc = 512;
constexpr int Lc = 512;
constexpr int Cc = 256;
constexpr int C4 = Cc / 4;   // 64 float4 columns == one wave of 16B lanes

__global__ __launch_bounds__(256) void lrf_kernel(const float4* __restrict__ x,
                                                  float4* __restrict__ out,
                                                  int T /* = L + pred_len */) {
    const int b  = blockIdx.x;
    const int c4 = threadIdx.x;   // 0..63
    const int y  = threadIdx.y;   // 0..3 (each y-slice is one wave)

    // ---- Phase 1: partial reductions over l (each wave handles l = y, y+4, ...)
    const float4* xb = x + (size_t)b * Lc * C4 + c4;
    float4 sy  = make_float4(0.f, 0.f, 0.f, 0.f);
    float4 sty = make_float4(0.f, 0.f, 0.f, 0.f);
    #pragma unroll 4
    for (int l = y; l < Lc; l += 4) {
        float4 v = xb[(size_t)l * C4];
        float fl = (float)l;
        sy.x += v.x; sy.y += v.y; sy.z += v.z; sy.w += v.w;
        sty.x = fmaf(fl, v.x, sty.x);
        sty.y = fmaf(fl, v.y, sty.y);
        sty.z = fmaf(fl, v.z, sty.z);
        sty.w = fmaf(fl, v.w, sty.w);
    }

    __shared__ float4 s_sy[4][C4];
    __shared__ float4 s_sty[4][C4];
    s_sy[y][c4]  = sy;
    s_sty[y][c4] = sty;
    __syncthreads();

    __shared__ float4 s_slope[C4];
    __shared__ float4 s_icept[C4];
    if (y == 0) {
        float4 SY  = s_sy[0][c4];
        float4 STY = s_sty[0][c4];
        #pragma unroll
        for (int k = 1; k < 4; ++k) {
            float4 a = s_sy[k][c4], t = s_sty[k][c4];
            SY.x += a.x;  SY.y += a.y;  SY.z += a.z;  SY.w += a.w;
            STY.x += t.x; STY.y += t.y; STY.z += t.z; STY.w += t.w;
        }
        const float mean_t    = 255.5f;               // sum_t / n
        const float inv_denom = 1.0f / 11184768.0f;   // exact integer in f32
        const float sum_t     = 130816.0f;
        const float inv_n     = 1.0f / 512.0f;
        float4 sl, ic;
        sl.x = (STY.x - mean_t * SY.x) * inv_denom;
        sl.y = (STY.y - mean_t * SY.y) * inv_denom;
        sl.z = (STY.z - mean_t * SY.z) * inv_denom;
        sl.w = (STY.w - mean_t * SY.w) * inv_denom;
        ic.x = (SY.x - sl.x * sum_t) * inv_n;
        ic.y = (SY.y - sl.y * sum_t) * inv_n;
        ic.z = (SY.z - sl.z * sum_t) * inv_n;
        ic.w = (SY.w - sl.w * sum_t) * inv_n;
        s_slope[c4] = sl;
        s_icept[c4] = ic;
    }
    __syncthreads();

    // ---- Phase 2: emit out[b, t, c] = slope*t + intercept, coalesced float4 rows
    const float4 sl = s_slope[c4];
    const float4 ic = s_icept[c4];
    float4* ob = out + (size_t)b * T * C4 + c4;
    for (int t = y; t < T; t += 4) {
        float ft = (float)t;
        float4 o;
        o.x = fmaf(sl.x, ft, ic.x);
        o.y = fmaf(sl.y, ft, ic.y);
        o.z = fmaf(sl.z, ft, ic.z);
        o.w = fmaf(sl.w, ft, ic.w);
        ob[(size_t)t * C4] = o;
    }
}

extern "C" void kernel_launch(void* const* d_in, const int* in_sizes, int n_in,
                              void* d_out, int out_size, void* d_ws, size_t ws_size,
                              hipStream_t stream) {
    (void)in_sizes; (void)n_in; (void)d_ws; (void)ws_size;
    const float4* x = (const float4*)d_in[0];
    float4* out = (float4*)d_out;
    const int T = out_size / (Bc * Cc);   // 608 = L + pred_len
    dim3 grid(Bc);
    dim3 block(C4, 4);
    hipLaunchKernelGGL(lrf_kernel, grid, block, 0, stream, x, out, T);
}